// Round 1
// 479.641 us; speedup vs baseline: 1.0495x; 1.0495x over previous
//
#include <hip/hip_runtime.h>
#include <hip/hip_bf16.h>

typedef __bf16 bf16;
typedef __bf16 bf16x8 __attribute__((ext_vector_type(8)));
typedef float f32x4 __attribute__((ext_vector_type(4)));

#define NU 20000
#define NO 10000
#define CDIM 256
#define TDIM 1536
#define EN 10000
#define VOCAB 101
#define MAXP 16
#define CAP 32

// output element offsets (FLOAT32 elements)
#define NODE_OFF 53760000LL
#define COL_OFF  53970000LL
#define TAB_OFF  54180000LL
#define F2P_OFF  54390000LL
#define NN_OFF   57750000LL

// ---- fused-grid partition: GEMM blocks FIRST so CUs grab long-running
// ---- MFMA work immediately; write-bound misc/idx blocks fill the
// ---- remaining occupancy slots and overlap with the GEMM.
#define GEMM_U_BLKS 314                        // 157 m-blocks x 2 n-blocks
#define GEMM_O_BLKS 158                        // 79 x 2
#define MISC_BLKS   22500
#define IDX_BLKS    840
#define MISC_OFF    (GEMM_U_BLKS + GEMM_O_BLKS)   // 472
#define IDX_OFF     (MISC_OFF + MISC_BLKS)        // 22972
#define TOTAL_BLKS  (IDX_OFF + IDX_BLKS)          // 23812

// ---------------- edge table build ----------------
__global__ void edges_fill(const int* __restrict__ edge, int* __restrict__ counts,
                           unsigned long long* __restrict__ pairs)
{
    int e = blockIdx.x * 256 + threadIdx.x;
    if (e >= EN) return;
    int child = edge[e];                      // edge_index[0][e], in [0, NO)
    unsigned parent = (unsigned)edge[EN + e]; // edge_index[1][e]
    int slot = atomicAdd(&counts[child], 1);
    if (slot < CAP)
        pairs[child * CAP + slot] = ((unsigned long long)(unsigned)e << 32) | parent;
}

__global__ void build_tbl(const int* __restrict__ counts,
                          const unsigned long long* __restrict__ pairs,
                          int* __restrict__ tbl)
{
    int mm = blockIdx.x * 256 + threadIdx.x;
    if (mm >= NO) return;
    int cnt = counts[mm];
    if (cnt > CAP) cnt = CAP;
    unsigned long long v[CAP];
    for (int i = 0; i < cnt; i++) v[i] = pairs[mm * CAP + i];
    // insertion sort by packed (edge_id<<32 | parent) => stable by original edge order
    for (int i = 1; i < cnt; i++) {
        unsigned long long key = v[i];
        int j = i - 1;
        while (j >= 0 && v[j] > key) { v[j + 1] = v[j]; j--; }
        v[j + 1] = key;
    }
#pragma unroll
    for (int j = 0; j < MAXP; j++)
        tbl[mm * MAXP + j] = (j < cnt) ? (int)(v[j] & 0xffffffffULL) : -1;
}

// ---------------- indices + f2p + num_nodes (float32 out) ----------------
__device__ __forceinline__ void idx_body(int iblk, const int* __restrict__ tbl,
                                         float* __restrict__ out)
{
    int i = iblk * 256 + threadIdx.x;
    if (i >= 210000) return;
    float nodev, colvf, tabv;
    int m = -1;
    if (i < 140000) {
        int n = i % 20000;
        nodev = (float)n; colvf = (float)(i / 20000); tabv = 0.f;
    } else {
        int i2 = i - 140000;
        m = i2 % 10000;
        nodev = (float)(20000 + m); colvf = (float)(7 + i2 / 10000); tabv = 1.f;
    }
    out[NODE_OFF + i] = nodev;
    out[COL_OFF + i]  = colvf;
    out[TAB_OFF + i]  = tabv;

    float h[16];
    if (m < 0) {
#pragma unroll
        for (int j = 0; j < 16; j++) h[j] = -1.f;
    } else {
#pragma unroll
        for (int j = 0; j < 16; j++) h[j] = (float)tbl[m * MAXP + j];
    }
    float4* dst = (float4*)&out[F2P_OFF + (long long)i * 16];
#pragma unroll
    for (int j = 0; j < 4; j++)
        dst[j] = *(const float4*)&h[j * 4];
    if (i == 0) out[NN_OFF] = 30000.f;
}

// ---------------- num + cat tokens (k = 0..5 of each table) ----------------
__device__ __forceinline__ void misc_body(int mb,
    const float* __restrict__ unum, const int* __restrict__ ucat,
    const float* __restrict__ onum, const int* __restrict__ ocat,
    const float* __restrict__ temb,
    const float* __restrict__ unw, const float* __restrict__ unb,
    const float* __restrict__ uctab, const float* __restrict__ ucol,
    const float* __restrict__ onw, const float* __restrict__ onb,
    const float* __restrict__ octab, const float* __restrict__ ocol,
    float* __restrict__ out)
{
    int t = threadIdx.x;
    int ridx = mb * 8 + (t >> 5);            // 0..179999 (exact)
    int c0 = (t & 31) * 8;
    bool isU = ridx < 120000;
    int k, n; long long orow;
    const float *num, *nw, *nb, *ctab, *colw, *te;
    const int* cat;
    if (isU) {
        k = ridx / 20000; n = ridx - k * 20000; orow = ridx;
        num = unum; cat = ucat; nw = unw; nb = unb; ctab = uctab; colw = ucol; te = temb;
    } else {
        int i2 = ridx - 120000;
        k = i2 / 10000; n = i2 - k * 10000; orow = (long long)ridx + 20000;
        num = onum; cat = ocat; nw = onw; nb = onb; ctab = octab; colw = ocol; te = temb + CDIM;
    }
    float colv[8], tev[8];
    *(float4*)&colv[0] = *(const float4*)&colw[k * CDIM + c0];
    *(float4*)&colv[4] = *(const float4*)&colw[k * CDIM + c0 + 4];
    *(float4*)&tev[0]  = *(const float4*)&te[c0];
    *(float4*)&tev[4]  = *(const float4*)&te[c0 + 4];
    float res[8];
    if (k < 3) {
        float v = num[n * 3 + k];
        float wv[8], bv[8];
        *(float4*)&wv[0] = *(const float4*)&nw[k * CDIM + c0];
        *(float4*)&wv[4] = *(const float4*)&nw[k * CDIM + c0 + 4];
        *(float4*)&bv[0] = *(const float4*)&nb[k * CDIM + c0];
        *(float4*)&bv[4] = *(const float4*)&nb[k * CDIM + c0 + 4];
#pragma unroll
        for (int j = 0; j < 8; j++) {
            float x = v * wv[j] + bv[j];
            float s = x / (1.f + __expf(-x));   // silu
            res[j] = s + colv[j] + tev[j];
        }
    } else {
        int cv = cat[n * 3 + (k - 3)];
        float tcv[8];
        *(float4*)&tcv[0] = *(const float4*)&ctab[((k - 3) * VOCAB + cv) * CDIM + c0];
        *(float4*)&tcv[4] = *(const float4*)&ctab[((k - 3) * VOCAB + cv) * CDIM + c0 + 4];
#pragma unroll
        for (int j = 0; j < 8; j++)
            res[j] = tcv[j] + colv[j] + tev[j];
    }
    *(float4*)&out[orow * CDIM + c0]     = *(const float4*)&res[0];
    *(float4*)&out[orow * CDIM + c0 + 4] = *(const float4*)&res[4];
}

// ---------------- text token GEMM: D = A(MxK) * W(NxK)^T + bias ----------------
// A, W are fp32 in HBM; converted to bf16 on the way into LDS; MFMA bf16; fp32 out.
// mblk/nblk passed explicitly so the two N-blocks of the same M-panel are
// ADJACENT in blockIdx order (A-tile refetch becomes a near-in-time L2/L3 hit).
__device__ __forceinline__ void gemm_body(
    const float* __restrict__ A, const float* __restrict__ W,
    const float* __restrict__ tbias, const float* __restrict__ colw,
    const float* __restrict__ temb, float* __restrict__ out,
    int M, long long out_row_base, int mblk, int nblk,
    bf16* As, bf16* Bs)
{
    constexpr int BK = 64, LDA = 72; // bf16 elems; +8 pad
    const int tid = threadIdx.x;
    const int m0 = mblk * 128;
    const int n0 = nblk * 128;
    const int w = tid >> 6, lane = tid & 63;
    const int wm = (w & 1) * 64, wn = (w >> 1) * 64;
    const int lrow = lane & 15, lquad = lane >> 4;

    f32x4 acc[4][4];
#pragma unroll
    for (int a = 0; a < 4; a++)
#pragma unroll
        for (int b = 0; b < 4; b++) acc[a][b] = (f32x4){0.f, 0.f, 0.f, 0.f};

    for (int k0 = 0; k0 < TDIM; k0 += BK) {
        __syncthreads();
#pragma unroll
        for (int i = 0; i < 8; i++) {
            int c = tid + i * 256;          // 0..2047 chunk id (4 floats each)
            int row = c >> 4;               // 0..127
            int col4 = (c & 15) << 2;       // 0..60
            int ga = m0 + row; if (ga >= M) ga = M - 1;  // clamp (stores predicated)
            float4 av = *(const float4*)&A[(size_t)ga * TDIM + k0 + col4];
            __attribute__((aligned(8))) bf16 ha[4] =
                {(bf16)av.x, (bf16)av.y, (bf16)av.z, (bf16)av.w};
            *(unsigned long long*)&As[row * LDA + col4] = *(const unsigned long long*)ha;
            float4 bv = *(const float4*)&W[(size_t)(n0 + row) * TDIM + k0 + col4];
            __attribute__((aligned(8))) bf16 hb[4] =
                {(bf16)bv.x, (bf16)bv.y, (bf16)bv.z, (bf16)bv.w};
            *(unsigned long long*)&Bs[row * LDA + col4] = *(const unsigned long long*)hb;
        }
        __syncthreads();
#pragma unroll
        for (int ks = 0; ks < 2; ks++) {
            bf16x8 afr[4], bfr[4];
#pragma unroll
            for (int mi = 0; mi < 4; mi++)
                afr[mi] = *(const bf16x8*)&As[(wm + mi * 16 + lrow) * LDA + ks * 32 + lquad * 8];
#pragma unroll
            for (int ni = 0; ni < 4; ni++)
                bfr[ni] = *(const bf16x8*)&Bs[(wn + ni * 16 + lrow) * LDA + ks * 32 + lquad * 8];
#pragma unroll
            for (int mi = 0; mi < 4; mi++)
#pragma unroll
                for (int ni = 0; ni < 4; ni++)
                    acc[mi][ni] = __builtin_amdgcn_mfma_f32_16x16x32_bf16(
                        afr[mi], bfr[ni], acc[mi][ni], 0, 0, 0);
        }
    }

    // epilogue: + txt_b[c] + col[6][c] + table_emb[c], write fp32
#pragma unroll
    for (int ni = 0; ni < 4; ni++) {
        int c = n0 + wn + ni * 16 + lrow;
        float bias = tbias[c] + colw[6 * CDIM + c] + temb[c];
#pragma unroll
        for (int mi = 0; mi < 4; mi++) {
            int mbase = m0 + wm + mi * 16 + lquad * 4;
#pragma unroll
            for (int r = 0; r < 4; r++) {
                int m = mbase + r;
                if (m < M)
                    out[(out_row_base + m) * CDIM + c] = acc[mi][ni][r] + bias;
            }
        }
    }
}

// ---------------- fused mega-kernel: gemmU | gemmO | misc | idx ----------------
__global__ __launch_bounds__(256) void mega(
    const float* __restrict__ users_num, const int* __restrict__ users_cat,
    const float* __restrict__ users_text,
    const float* __restrict__ orders_num, const int* __restrict__ orders_cat,
    const float* __restrict__ orders_text,
    const float* __restrict__ temb,
    const float* __restrict__ unw, const float* __restrict__ unb,
    const float* __restrict__ uctab, const float* __restrict__ utw,
    const float* __restrict__ utb, const float* __restrict__ ucol,
    const float* __restrict__ onw, const float* __restrict__ onb,
    const float* __restrict__ octab, const float* __restrict__ otw,
    const float* __restrict__ otb, const float* __restrict__ ocol,
    const int* __restrict__ tbl, float* __restrict__ out)
{
    __shared__ bf16 As[128 * 72];
    __shared__ bf16 Bs[128 * 72];
    int b = blockIdx.x;
    if (b < GEMM_U_BLKS) {
        gemm_body(users_text, utw, utb, ucol, temb, out,
                  NU, 120000LL, b >> 1, b & 1, As, Bs);
    } else if (b < MISC_OFF) {
        int bb = b - GEMM_U_BLKS;
        gemm_body(orders_text, otw, otb, ocol, temb + CDIM, out,
                  NO, 200000LL, bb >> 1, bb & 1, As, Bs);
    } else if (b < IDX_OFF) {
        misc_body(b - MISC_OFF, users_num, users_cat, orders_num, orders_cat,
                  temb, unw, unb, uctab, ucol, onw, onb, octab, ocol, out);
    } else {
        idx_body(b - IDX_OFF, tbl, out);
    }
}

extern "C" void kernel_launch(void* const* d_in, const int* in_sizes, int n_in,
                              void* d_out, int out_size, void* d_ws, size_t ws_size,
                              hipStream_t stream)
{
    const float* users_num   = (const float*)d_in[0];
    const int*   users_cat   = (const int*)d_in[1];
    const float* users_text  = (const float*)d_in[2];
    const float* orders_num  = (const float*)d_in[3];
    const int*   orders_cat  = (const int*)d_in[4];
    const float* orders_text = (const float*)d_in[5];
    const int*   edge_index  = (const int*)d_in[6];
    const float* table_emb   = (const float*)d_in[7];
    const float* u_num_w   = (const float*)d_in[8];
    const float* u_num_b   = (const float*)d_in[9];
    const float* u_cat_tab = (const float*)d_in[10];
    const float* u_txt_w   = (const float*)d_in[11];
    const float* u_txt_b   = (const float*)d_in[12];
    const float* u_col     = (const float*)d_in[13];
    const float* o_num_w   = (const float*)d_in[14];
    const float* o_num_b   = (const float*)d_in[15];
    const float* o_cat_tab = (const float*)d_in[16];
    const float* o_txt_w   = (const float*)d_in[17];
    const float* o_txt_b   = (const float*)d_in[18];
    const float* o_col     = (const float*)d_in[19];
    float* out = (float*)d_out;

    // workspace: counts (64KB slot) | pairs (NO*CAP u64 = 2.56MB) | tbl (NO*16 int = 640KB)
    int* counts = (int*)d_ws;
    unsigned long long* pairs = (unsigned long long*)((char*)d_ws + 65536);
    int* tbl = (int*)((char*)d_ws + 65536 + (size_t)NO * CAP * 8);

    hipMemsetAsync(counts, 0, NO * sizeof(int), stream);
    edges_fill<<<(EN + 255) / 256, 256, 0, stream>>>(edge_index, counts, pairs);
    build_tbl<<<(NO + 255) / 256, 256, 0, stream>>>(counts, pairs, tbl);
    mega<<<TOTAL_BLKS, 256, 0, stream>>>(
        users_num, users_cat, users_text, orders_num, orders_cat, orders_text,
        table_emb, u_num_w, u_num_b, u_cat_tab, u_txt_w, u_txt_b, u_col,
        o_num_w, o_num_b, o_cat_tab, o_txt_w, o_txt_b, o_col, tbl, out);
}